// Round 2
// baseline (617.607 us; speedup 1.0000x reference)
//
#include <hip/hip_runtime.h>
#include <hip/hip_bf16.h>

#define NS 32
#define NE 32
#define BB 64
#define DD 1024
#define HH 16
#define SB (NS * BB)  // 2048

typedef __attribute__((ext_vector_type(4))) float f32x4;
typedef __attribute__((ext_vector_type(8))) short short8;

static __device__ __forceinline__ unsigned short f2bf(float f) {
  union { float f; unsigned int u; } c{f};
  unsigned int u = c.u;
  return (unsigned short)((u + 0x7FFFu + ((u >> 16) & 1u)) >> 16);  // RNE
}

// packed RNE f32x2 -> bf16x2 (v_cvt_pk_bf16_f32)
static __device__ __forceinline__ unsigned int pk2bf(float a, float b) {
  __hip_bfloat162 h = __float22bfloat162_rn(float2{a, b});
  union { __hip_bfloat162 h; unsigned int u; } c{h};
  return c.u;
}

// ---------- k0: merged prep ----------
// blocks 0..63: rT[h][d] = sum_j q[h*64+j]*Wk[h*64+j][d], q = (Wq@query+bq)/8
// blocks 64..2111: bf16 conversion of Wv and W_out
extern "C" __global__ __launch_bounds__(256)
void k0_prep(const float* __restrict__ ipw, const float* __restrict__ ipb,
             const float* __restrict__ query, const float* __restrict__ opw,
             unsigned short* __restrict__ rT, unsigned short* __restrict__ wv,
             unsigned short* __restrict__ wo) {
  __shared__ float qh[64];
  const int blk = blockIdx.x;
  const int t = threadIdx.x;
  if (blk < 64) {
    const int h = blk >> 2, dpart = blk & 3;
    const int wu = t >> 6, ln = t & 63;
    // phase A: q_h (64 dots of length 1024), 4 waves x 16 rows each
    for (int jj = 0; jj < 16; ++jj) {
      int j = wu * 16 + jj;
      const float* row = ipw + (size_t)(h * 64 + j) * DD;
      float s = 0.f;
      for (int k = ln; k < DD; k += 64) s += row[k] * query[k];
      #pragma unroll
      for (int off = 32; off; off >>= 1) s += __shfl_xor(s, off);
      if (ln == 0) qh[j] = (s + ipb[h * 64 + j]) * 0.125f;  // scale 1/sqrt(64)
    }
    __syncthreads();
    // phase B: rT[h][d] for d-chunk
    const float* wk = ipw + (size_t)DD * DD;
    const int d = dpart * 256 + t;
    float s = 0.f;
    #pragma unroll 8
    for (int j = 0; j < 64; ++j)
      s += qh[j] * wk[(size_t)(h * 64 + j) * DD + d];
    rT[h * DD + d] = f2bf(s);
  } else {
    const int i = (blk - 64) * 256 + t;  // float4 index, 0..524287
    const float* wv_f = ipw + (size_t)2 * DD * DD;
    if (i < 262144) {
      float4 v = reinterpret_cast<const float4*>(wv_f)[i];
      reinterpret_cast<uint2*>(wv)[i] = uint2{pk2bf(v.x, v.y), pk2bf(v.z, v.w)};
    } else {
      const int j = i - 262144;
      float4 v = reinterpret_cast<const float4*>(opw)[j];
      reinterpret_cast<uint2*>(wo)[j] = uint2{pk2bf(v.x, v.y), pk2bf(v.z, v.w)};
    }
  }
}

// ---------- k1: per-(s,b): scores -> softmax -> agg[sb][h][d] (bf16) ----------
extern "C" __global__ __launch_bounds__(512, 4)
void k1_scores_agg(const float* __restrict__ ent,
                   const unsigned char* __restrict__ mask,
                   const unsigned short* __restrict__ rT,
                   unsigned short* __restrict__ agg,
                   unsigned char* __restrict__ flags) {
  __shared__ unsigned short elds[NE * DD];        // 64 KB, XOR-swizzled
  __shared__ float slds[NE][HH];                  // scores
  __shared__ unsigned short attnT[HH][NE];        // bf16 attn, [h][e]
  __shared__ unsigned char mlds[NE];

  const int sb = blockIdx.x;
  const int s = sb >> 6, b = sb & 63;
  const int t = threadIdx.x;
  const int lane = t & 63;
  const int wave = t >> 6;

  // stage entities: fp32 global -> bf16 LDS (swizzle elem^((e&7)<<3))
  const float* base = ent + ((size_t)(s * NE) * BB + b) * DD;
  #pragma unroll
  for (int i = 0; i < 16; ++i) {
    int f4 = t + 512 * i;          // 0..8191
    int e = f4 >> 8;
    int d0 = (f4 & 255) << 2;
    float4 v = *reinterpret_cast<const float4*>(base + (size_t)e * (BB * DD) + d0);
    int sidx = ((e << 10) + d0) ^ ((e & 7) << 3);
    *reinterpret_cast<uint2*>(&elds[sidx]) = uint2{pk2bf(v.x, v.y), pk2bf(v.z, v.w)};
  }
  if (t < NE) mlds[t] = mask[(size_t)(s * NE + t) * BB + b];
  __syncthreads();

  // scores: waves 0,1 -> scores[e][h], e-tile = wave. A=ent(LDS), B=rT(L2). K=1024.
  if (wave < 2) {
    const int g = lane >> 4, m = lane & 15;
    const int e = wave * 16 + m;
    f32x4 acc = {0.f, 0.f, 0.f, 0.f};
    #pragma unroll 4
    for (int ks = 0; ks < 32; ++ks) {
      int d0 = (ks << 5) + (g << 3);
      short8 a = *reinterpret_cast<const short8*>(&elds[((e << 10) + d0) ^ ((e & 7) << 3)]);
      short8 bb = *reinterpret_cast<const short8*>(rT + (m << 10) + d0);
      acc = __builtin_amdgcn_mfma_f32_16x16x32_bf16(a, bb, acc, 0, 0, 0);
    }
    #pragma unroll
    for (int r = 0; r < 4; ++r)
      slds[wave * 16 + (g << 2) + r][m] = acc[r];
  }
  __syncthreads();

  // softmax over e per (h): half-wave owns one h (32 lanes = 32 e's)
  {
    const int h = t >> 5, e = t & 31;
    bool msk = mlds[e] != 0;
    float v = msk ? -3.4e38f : slds[e][h];
    float mx = v;
    #pragma unroll
    for (int off = 16; off; off >>= 1) mx = fmaxf(mx, __shfl_xor(mx, off));
    float ex = msk ? 0.f : __expf(v - mx);
    float sm = ex;
    #pragma unroll
    for (int off = 16; off; off >>= 1) sm += __shfl_xor(sm, off);
    float at = sm > 0.f ? ex / sm : 0.f;
    attnT[h][e] = f2bf(at);
  }
  if (t == 0) {
    unsigned char all = 1;
    for (int e = 0; e < NE; ++e) all &= (mlds[e] ? (unsigned char)1 : (unsigned char)0);
    flags[sb] = all;
  }
  __syncthreads();

  // agg[h][d] = sum_e attn[h][e]*ent[e][d]: one K=32 MFMA per 16-d tile; 8 tiles/wave
  {
    const int g = lane >> 4, c = lane & 15;
    short8 a = *reinterpret_cast<const short8*>(&attnT[c][g << 3]);  // A[m=h=c][k=8g+j]
    unsigned short* ob = agg + ((size_t)sb << 14);
    #pragma unroll
    for (int q = 0; q < 8; ++q) {
      const int nt = (wave << 3) + q;
      const int d = (nt << 4) + c;
      short8 bb;
      #pragma unroll
      for (int j = 0; j < 8; ++j) {
        int e = (g << 3) + j;  // same k-order as A
        bb[j] = (short)elds[((e << 10) + d) ^ ((e & 7) << 3)];
      }
      f32x4 acc = {0.f, 0.f, 0.f, 0.f};
      acc = __builtin_amdgcn_mfma_f32_16x16x32_bf16(a, bb, acc, 0, 0, 0);
      #pragma unroll
      for (int r = 0; r < 4; ++r)
        ob[(((g << 2) + r) << 10) + d] = f2bf(acc[r]);  // agg[h=4g+r][d]
    }
  }
}

// ---------- k2: ctx[sb][h*64+d'] = agg[sb][h][:] @ Wv_h^T + bv ----------
extern "C" __global__ __launch_bounds__(256, 4)
void k2_ctx(const unsigned short* __restrict__ agg,
            const unsigned short* __restrict__ wv,
            const float* __restrict__ bv,
            unsigned short* __restrict__ ctx) {
  const int mt = blockIdx.x;   // sb tile of 64
  const int h = blockIdx.y;    // head
  const int t = threadIdx.x, lane = t & 63, wave = t >> 6;
  const int g = lane >> 4, c = lane & 15;
  const int row0 = mt * 64 + wave * 16;
  f32x4 acc[4] = {{0,0,0,0},{0,0,0,0},{0,0,0,0},{0,0,0,0}};
  #pragma unroll 2
  for (int ks = 0; ks < 32; ++ks) {
    int k0 = (ks << 5) + (g << 3);
    short8 a = *reinterpret_cast<const short8*>(agg + ((size_t)((row0 + c) * 16 + h) << 10) + k0);
    #pragma unroll
    for (int nt = 0; nt < 4; ++nt) {
      short8 bb = *reinterpret_cast<const short8*>(wv + ((size_t)(h * 64 + nt * 16 + c) << 10) + k0);
      acc[nt] = __builtin_amdgcn_mfma_f32_16x16x32_bf16(a, bb, acc[nt], 0, 0, 0);
    }
  }
  #pragma unroll
  for (int nt = 0; nt < 4; ++nt)
    #pragma unroll
    for (int r = 0; r < 4; ++r) {
      int col = h * 64 + nt * 16 + c;
      ctx[((size_t)(row0 + (g << 2) + r) << 10) + col] = f2bf(acc[nt][r] + bv[col]);
    }
}

// ---------- k3: out[sb][n] = ctx[sb][:] @ W_out^T + b_out (fp32), masked rows -> 0 ----------
extern "C" __global__ __launch_bounds__(256, 4)
void k3_out(const unsigned short* __restrict__ ctx,
            const unsigned short* __restrict__ wo,
            const float* __restrict__ bias,
            const unsigned char* __restrict__ flags,
            float* __restrict__ out) {
  const int mt = blockIdx.x;
  const int n0 = blockIdx.y * 64;
  const int t = threadIdx.x, lane = t & 63, wave = t >> 6;
  const int g = lane >> 4, c = lane & 15;
  const int row0 = mt * 64 + wave * 16;
  f32x4 acc[4] = {{0,0,0,0},{0,0,0,0},{0,0,0,0},{0,0,0,0}};
  #pragma unroll 2
  for (int ks = 0; ks < 32; ++ks) {
    int k0 = (ks << 5) + (g << 3);
    short8 a = *reinterpret_cast<const short8*>(ctx + ((size_t)(row0 + c) << 10) + k0);
    #pragma unroll
    for (int nt = 0; nt < 4; ++nt) {
      short8 bb = *reinterpret_cast<const short8*>(wo + ((size_t)(n0 + nt * 16 + c) << 10) + k0);
      acc[nt] = __builtin_amdgcn_mfma_f32_16x16x32_bf16(a, bb, acc[nt], 0, 0, 0);
    }
  }
  #pragma unroll
  for (int nt = 0; nt < 4; ++nt)
    #pragma unroll
    for (int r = 0; r < 4; ++r) {
      int row = row0 + (g << 2) + r;
      int col = n0 + nt * 16 + c;
      float v = acc[nt][r] + bias[col];
      if (flags[row]) v = 0.f;
      out[(size_t)row * DD + col] = v;
    }
}

extern "C" void kernel_launch(void* const* d_in, const int* in_sizes, int n_in,
                              void* d_out, int out_size, void* d_ws, size_t ws_size,
                              hipStream_t stream) {
  const float* ent = (const float*)d_in[0];
  const unsigned char* mask = (const unsigned char*)d_in[1];
  const float* query = (const float*)d_in[3];
  const float* ipw = (const float*)d_in[4];
  const float* ipb = (const float*)d_in[5];
  const float* opw = (const float*)d_in[6];
  const float* opb = (const float*)d_in[7];
  float* out = (float*)d_out;

  char* ws = (char*)d_ws;
  unsigned char* flags = (unsigned char*)(ws + 4096); // 2 KB
  unsigned short* rT = (unsigned short*)(ws + 8192);  // 32 KB
  unsigned short* wv = (unsigned short*)(ws + 65536);                 // 2 MB
  unsigned short* wo = (unsigned short*)(ws + 65536 + (2u << 20));    // 2 MB
  unsigned short* ctx = (unsigned short*)(ws + 65536 + (4u << 20));   // 4 MB
  unsigned short* agg = (unsigned short*)(ws + 65536 + (8u << 20));   // 64 MB

  hipLaunchKernelGGL(k0_prep, dim3(64 + 2048), dim3(256), 0, stream,
                     ipw, ipb, query, opw, rT, wv, wo);
  hipLaunchKernelGGL(k1_scores_agg, dim3(SB), dim3(512), 0, stream,
                     ent, mask, rT, agg, flags);
  hipLaunchKernelGGL(k2_ctx, dim3(32, 16), dim3(256), 0, stream,
                     agg, wv, ipb + 2 * DD, ctx);
  hipLaunchKernelGGL(k3_out, dim3(32, 16), dim3(256), 0, stream,
                     ctx, wo, opb, flags, out);
}

// Round 4
// 593.269 us; speedup vs baseline: 1.0410x; 1.0410x over previous
//
#include <hip/hip_runtime.h>
#include <hip/hip_bf16.h>

#define NS 32
#define NE 32
#define BB 64
#define DD 1024
#define HH 16
#define SB (NS * BB)  // 2048

typedef __attribute__((ext_vector_type(4))) float f32x4;
typedef __attribute__((ext_vector_type(8))) short short8;

static __device__ __forceinline__ unsigned short f2bf(float f) {
  union { float f; unsigned int u; } c{f};
  unsigned int u = c.u;
  return (unsigned short)((u + 0x7FFFu + ((u >> 16) & 1u)) >> 16);  // RNE
}

// packed RNE f32x2 -> bf16x2 (v_cvt_pk_bf16_f32)
static __device__ __forceinline__ unsigned int pk2bf(float a, float b) {
  __hip_bfloat162 h = __float22bfloat162_rn(float2{a, b});
  union { __hip_bfloat162 h; unsigned int u; } c{h};
  return c.u;
}

// ---------- k0: merged prep ----------
// blocks 0..63: rT[h][d] = sum_j q[h*64+j]*Wk[h*64+j][d], q = (Wq@query+bq)/8
// blocks 64..2111: bf16 conversion of Wv and W_out
extern "C" __global__ __launch_bounds__(256)
void k0_prep(const float* __restrict__ ipw, const float* __restrict__ ipb,
             const float* __restrict__ query, const float* __restrict__ opw,
             unsigned short* __restrict__ rT, unsigned short* __restrict__ wv,
             unsigned short* __restrict__ wo) {
  __shared__ float qh[64];
  const int blk = blockIdx.x;
  const int t = threadIdx.x;
  if (blk < 64) {
    const int h = blk >> 2, dpart = blk & 3;
    const int wu = t >> 6, ln = t & 63;
    for (int jj = 0; jj < 16; ++jj) {
      int j = wu * 16 + jj;
      const float* row = ipw + (size_t)(h * 64 + j) * DD;
      float s = 0.f;
      for (int k = ln; k < DD; k += 64) s += row[k] * query[k];
      #pragma unroll
      for (int off = 32; off; off >>= 1) s += __shfl_xor(s, off);
      if (ln == 0) qh[j] = (s + ipb[h * 64 + j]) * 0.125f;  // scale 1/sqrt(64)
    }
    __syncthreads();
    const float* wk = ipw + (size_t)DD * DD;
    const int d = dpart * 256 + t;
    float s = 0.f;
    #pragma unroll 8
    for (int j = 0; j < 64; ++j)
      s += qh[j] * wk[(size_t)(h * 64 + j) * DD + d];
    rT[h * DD + d] = f2bf(s);
  } else {
    const int i = (blk - 64) * 256 + t;  // float4 index
    const float* wv_f = ipw + (size_t)2 * DD * DD;
    if (i < 262144) {
      float4 v = reinterpret_cast<const float4*>(wv_f)[i];
      reinterpret_cast<uint2*>(wv)[i] = uint2{pk2bf(v.x, v.y), pk2bf(v.z, v.w)};
    } else {
      const int j = i - 262144;
      float4 v = reinterpret_cast<const float4*>(opw)[j];
      reinterpret_cast<uint2*>(wo)[j] = uint2{pk2bf(v.x, v.y), pk2bf(v.z, v.w)};
    }
  }
}

// ---------- k1: per-(s,b): scores -> softmax -> aggT[h][sb][d] (bf16) ----------
extern "C" __global__ __launch_bounds__(512, 4)
void k1_scores_agg(const float* __restrict__ ent,
                   const unsigned char* __restrict__ mask,
                   const unsigned short* __restrict__ rT,
                   unsigned short* __restrict__ aggT,
                   unsigned char* __restrict__ flags) {
  __shared__ unsigned short elds[NE * DD];        // 64 KB, XOR-swizzled; reused as out-stage
  __shared__ float sldsp[4][NE][HH + 1];          // K-partial scores, padded
  __shared__ unsigned short attnT[HH][NE];        // bf16 attn, [h][e]
  __shared__ unsigned char mlds[NE];

  const int sb = blockIdx.x;
  const int s = sb >> 6, b = sb & 63;
  const int t = threadIdx.x;
  const int lane = t & 63;
  const int wave = t >> 6;
  const int g = lane >> 4;

  // stage entities: fp32 global -> bf16 LDS (swizzle elem^((e&7)<<3))
  const float* base = ent + ((size_t)(s * NE) * BB + b) * DD;
  #pragma unroll
  for (int i = 0; i < 16; ++i) {
    int f4 = t + 512 * i;          // 0..8191
    int e = f4 >> 8;
    int d0 = (f4 & 255) << 2;
    float4 v = *reinterpret_cast<const float4*>(base + (size_t)e * (BB * DD) + d0);
    int sidx = ((e << 10) + d0) ^ ((e & 7) << 3);
    *reinterpret_cast<uint2*>(&elds[sidx]) = uint2{pk2bf(v.x, v.y), pk2bf(v.z, v.w)};
  }
  if (t < NE) mlds[t] = mask[(size_t)(s * NE + t) * BB + b];
  __syncthreads();

  // scores: all 8 waves. wave = (kq<<1)|et: e-tile et (16 e's), K-quarter kq (8 ks each).
  {
    const int m = lane & 15;
    const int et = wave & 1, kq = wave >> 1;
    const int e = et * 16 + m;
    f32x4 acc = {0.f, 0.f, 0.f, 0.f};
    #pragma unroll
    for (int i = 0; i < 8; ++i) {
      int ks = kq * 8 + i;
      int d0 = (ks << 5) + (g << 3);
      short8 a = *reinterpret_cast<const short8*>(&elds[((e << 10) + d0) ^ ((e & 7) << 3)]);
      short8 bb = *reinterpret_cast<const short8*>(rT + (m << 10) + d0);
      acc = __builtin_amdgcn_mfma_f32_16x16x32_bf16(a, bb, acc, 0, 0, 0);
    }
    #pragma unroll
    for (int r = 0; r < 4; ++r)
      sldsp[kq][et * 16 + (g << 2) + r][m] = acc[r];
  }
  __syncthreads();

  // softmax over e per h: half-wave owns one h (32 lanes = 32 e's)
  {
    const int h = t >> 5, e = t & 31;
    bool msk = mlds[e] != 0;
    float v = msk ? -3.4e38f
                  : (sldsp[0][e][h] + sldsp[1][e][h] + sldsp[2][e][h] + sldsp[3][e][h]);
    float mx = v;
    #pragma unroll
    for (int off = 16; off; off >>= 1) mx = fmaxf(mx, __shfl_xor(mx, off));
    float ex = msk ? 0.f : __expf(v - mx);
    float sm = ex;
    #pragma unroll
    for (int off = 16; off; off >>= 1) sm += __shfl_xor(sm, off);
    float at = sm > 0.f ? ex / sm : 0.f;
    attnT[h][e] = f2bf(at);
  }
  if (t == 0) {
    unsigned char all = 1;
    for (int e = 0; e < NE; ++e) all &= (mlds[e] ? (unsigned char)1 : (unsigned char)0);
    flags[sb] = all;
  }
  __syncthreads();

  // agg[h][d] = sum_e attn[h][e]*ent[e][d] -> registers (8 q-tiles/wave)
  f32x4 qacc[8];
  {
    const int c = lane & 15;
    short8 a = *reinterpret_cast<const short8*>(&attnT[c][g << 3]);  // A[m=h=c][k=8g+j]
    #pragma unroll
    for (int q = 0; q < 8; ++q) {
      const int nt = (wave << 3) + q;
      const int d = (nt << 4) + c;
      short8 bb;
      #pragma unroll
      for (int j = 0; j < 8; ++j) {
        int e = (g << 3) + j;  // same k-order as A
        bb[j] = (short)elds[((e << 10) + d) ^ ((e & 7) << 3)];
      }
      f32x4 z = {0.f, 0.f, 0.f, 0.f};
      qacc[q] = __builtin_amdgcn_mfma_f32_16x16x32_bf16(a, bb, z, 0, 0, 0);
    }
  }
  __syncthreads();   // all elds reads complete -> safe to overwrite

  // stash results in elds as aout[h][d] (u16), then coalesced global write
  {
    const int c = lane & 15;
    #pragma unroll
    for (int q = 0; q < 8; ++q) {
      const int d = (((wave << 3) + q) << 4) + c;
      #pragma unroll
      for (int r = 0; r < 4; ++r)
        elds[(((g << 2) + r) << 10) + d] = f2bf(qacc[q][r]);
    }
  }
  __syncthreads();
  {
    const unsigned long long* src64 = reinterpret_cast<const unsigned long long*>(elds);
    #pragma unroll
    for (int p = 0; p < 8; ++p) {
      int off = p * 512 + t;           // u64 index, 0..4095
      int h = off >> 8;
      int d = (off << 2) & 1023;
      *reinterpret_cast<unsigned long long*>(
          aggT + (((size_t)h * SB + sb) << 10) + d) = src64[off];
    }
  }
}

// ---------- k2: ctx[sb][h*64+n'] = aggT[h][sb][:] @ Wv_h^T + bv ----------
extern "C" __global__ __launch_bounds__(256, 4)
void k2_ctx(const unsigned short* __restrict__ aggT,
            const unsigned short* __restrict__ wv,
            const float* __restrict__ bv,
            unsigned short* __restrict__ ctx) {
  __shared__ unsigned short alds[64 * 256];  // 32 KB, XOR-swizzled [row][k-chunk]
  const int mt = blockIdx.x;   // sb tile of 64
  const int h = blockIdx.y;    // head
  const int t = threadIdx.x, lane = t & 63, w = t >> 6;
  const int g = lane >> 4, c = lane & 15;
  const char* abase = reinterpret_cast<const char*>(aggT + (((size_t)h * SB + mt * 64) << 10));
  f32x4 acc[4] = {{0,0,0,0},{0,0,0,0},{0,0,0,0},{0,0,0,0}};
  for (int kc = 0; kc < 4; ++kc) {
    __syncthreads();
    // stage 64 rows x 256 k (32 KB), coalesced 512-B runs per row
    #pragma unroll
    for (int it = 0; it < 8; ++it) {
      int o = it * 4096 + t * 16;      // byte offset in tile
      int row = o >> 9;
      int inb = o & 511;
      uint4 v = *reinterpret_cast<const uint4*>(abase + (size_t)row * 2048 + kc * 512 + inb);
      *reinterpret_cast<uint4*>(
          reinterpret_cast<char*>(alds) + row * 512 + (inb ^ ((row & 7) << 4))) = v;
    }
    __syncthreads();
    #pragma unroll
    for (int ks = 0; ks < 8; ++ks) {
      int row = w * 16 + c;
      int inb = (ks * 32 + g * 8) * 2;
      short8 a = *reinterpret_cast<const short8*>(
          reinterpret_cast<const char*>(alds) + row * 512 + (inb ^ ((row & 7) << 4)));
      int kg = kc * 256 + ks * 32 + g * 8;
      #pragma unroll
      for (int nt = 0; nt < 4; ++nt) {
        short8 bb = *reinterpret_cast<const short8*>(wv + ((size_t)(h * 64 + nt * 16 + c) << 10) + kg);
        acc[nt] = __builtin_amdgcn_mfma_f32_16x16x32_bf16(a, bb, acc[nt], 0, 0, 0);
      }
    }
  }
  const int row0 = mt * 64 + w * 16;
  #pragma unroll
  for (int nt = 0; nt < 4; ++nt)
    #pragma unroll
    for (int r = 0; r < 4; ++r) {
      int col = h * 64 + nt * 16 + c;
      ctx[((size_t)(row0 + (g << 2) + r) << 10) + col] = f2bf(acc[nt][r] + bv[col]);
    }
}

// ---------- k3: out[sb][n] = ctx[sb][:] @ W_out^T + b_out (fp32), masked rows -> 0 ----------
extern "C" __global__ __launch_bounds__(256, 4)
void k3_out(const unsigned short* __restrict__ ctx,
            const unsigned short* __restrict__ wo,
            const float* __restrict__ bias,
            const unsigned char* __restrict__ flags,
            float* __restrict__ out) {
  const int mt = blockIdx.x;
  const int n0 = blockIdx.y * 64;
  const int t = threadIdx.x, lane = t & 63, wave = t >> 6;
  const int g = lane >> 4, c = lane & 15;
  const int row0 = mt * 64 + wave * 16;
  f32x4 acc[4] = {{0,0,0,0},{0,0,0,0},{0,0,0,0},{0,0,0,0}};
  #pragma unroll 2
  for (int ks = 0; ks < 32; ++ks) {
    int k0 = (ks << 5) + (g << 3);
    short8 a = *reinterpret_cast<const short8*>(ctx + ((size_t)(row0 + c) << 10) + k0);
    #pragma unroll
    for (int nt = 0; nt < 4; ++nt) {
      short8 bb = *reinterpret_cast<const short8*>(wo + ((size_t)(n0 + nt * 16 + c) << 10) + k0);
      acc[nt] = __builtin_amdgcn_mfma_f32_16x16x32_bf16(a, bb, acc[nt], 0, 0, 0);
    }
  }
  #pragma unroll
  for (int nt = 0; nt < 4; ++nt)
    #pragma unroll
    for (int r = 0; r < 4; ++r) {
      int row = row0 + (g << 2) + r;
      int col = n0 + nt * 16 + c;
      float v = acc[nt][r] + bias[col];
      if (flags[row]) v = 0.f;
      out[(size_t)row * DD + col] = v;
    }
}

extern "C" void kernel_launch(void* const* d_in, const int* in_sizes, int n_in,
                              void* d_out, int out_size, void* d_ws, size_t ws_size,
                              hipStream_t stream) {
  const float* ent = (const float*)d_in[0];
  const unsigned char* mask = (const unsigned char*)d_in[1];
  const float* query = (const float*)d_in[3];
  const float* ipw = (const float*)d_in[4];
  const float* ipb = (const float*)d_in[5];
  const float* opw = (const float*)d_in[6];
  const float* opb = (const float*)d_in[7];
  float* out = (float*)d_out;

  char* ws = (char*)d_ws;
  unsigned char* flags = (unsigned char*)(ws + 4096); // 2 KB
  unsigned short* rT = (unsigned short*)(ws + 8192);  // 32 KB
  unsigned short* wv = (unsigned short*)(ws + 65536);                 // 2 MB
  unsigned short* wo = (unsigned short*)(ws + 65536 + (2u << 20));    // 2 MB
  unsigned short* ctx = (unsigned short*)(ws + 65536 + (4u << 20));   // 4 MB
  unsigned short* aggT = (unsigned short*)(ws + 65536 + (8u << 20));  // 64 MB [h][sb][d]

  hipLaunchKernelGGL(k0_prep, dim3(64 + 2048), dim3(256), 0, stream,
                     ipw, ipb, query, opw, rT, wv, wo);
  hipLaunchKernelGGL(k1_scores_agg, dim3(SB), dim3(512), 0, stream,
                     ent, mask, rT, aggT, flags);
  hipLaunchKernelGGL(k2_ctx, dim3(32, 16), dim3(256), 0, stream,
                     aggT, wv, ipb + 2 * DD, ctx);
  hipLaunchKernelGGL(k3_out, dim3(32, 16), dim3(256), 0, stream,
                     ctx, wo, opb, flags, out);
}